// Round 8
// baseline (150.201 us; speedup 1.0000x reference)
//
#include <hip/hip_runtime.h>
#include <hip/hip_bf16.h>

#define NUM_RATINGS 10
#define CH 4   // tiles per wave

typedef short bf16x8 __attribute__((ext_vector_type(8)));
typedef float f32x4 __attribute__((ext_vector_type(4)));

// ---------------- d_ws layout ----------------
// bytes [0..255]        : int cnt[16], poff[16], cursor[16], rend[16]
// bytes [256..82175]    : bf16x8 wf[10*8*64]   (80 KiB W fragments)
// bytes [82176.. ]      : int2 meta[E]  (node, inv_c bits), rating-sorted

__global__ void k_zero(int* __restrict__ cnt) {
    if (threadIdx.x < 16) cnt[threadIdx.x] = 0;
}

__global__ void k_hist(const int* __restrict__ rating, int n, int* __restrict__ cnt) {
    __shared__ int h[NUM_RATINGS];
    if (threadIdx.x < NUM_RATINGS) h[threadIdx.x] = 0;
    __syncthreads();
    int b0 = blockIdx.x * (blockDim.x * 4) + threadIdx.x;
    #pragma unroll
    for (int i = 0; i < 4; ++i) {
        int e = b0 + i * blockDim.x;
        if (e < n) atomicAdd(&h[rating[e]], 1);
    }
    __syncthreads();
    if (threadIdx.x < NUM_RATINGS) atomicAdd(&cnt[threadIdx.x], h[threadIdx.x]);
}

__global__ void k_prefix(const int* __restrict__ cnt, int* __restrict__ poff,
                         int* __restrict__ cursor, int* __restrict__ rend) {
    if (threadIdx.x == 0 && blockIdx.x == 0) {
        int s = 0;
        for (int r = 0; r < NUM_RATINGS; ++r) {
            poff[r] = s; cursor[r] = s;
            rend[r] = s + cnt[r];
            s += (cnt[r] + 15) & ~15;
        }
        poff[NUM_RATINGS] = s;
    }
}

// stable-ish block scatter (within-block order preserved; edge ids within a
// bucket stay ascending per block, blocks claim ranges atomically)
__global__ void k_scatter(const int* __restrict__ rating, const int* __restrict__ enode,
                          const float* __restrict__ invc, int n,
                          int* __restrict__ cursor, int2* __restrict__ meta) {
    __shared__ int h[NUM_RATINGS];
    __shared__ int base[NUM_RATINGS];
    if (threadIdx.x < NUM_RATINGS) h[threadIdx.x] = 0;
    __syncthreads();
    int rk[4], rr[4], ee[4];
    int b0 = blockIdx.x * (blockDim.x * 4) + threadIdx.x;
    #pragma unroll
    for (int i = 0; i < 4; ++i) {
        int e = b0 + i * blockDim.x;
        ee[i] = e;
        if (e < n) {
            int r = rating[e];
            rr[i] = r;
            rk[i] = atomicAdd(&h[r], 1);
        }
    }
    __syncthreads();
    if (threadIdx.x < NUM_RATINGS)
        base[threadIdx.x] = atomicAdd(&cursor[threadIdx.x], h[threadIdx.x]);
    __syncthreads();
    #pragma unroll
    for (int i = 0; i < 4; ++i)
        if (ee[i] < n)
            meta[base[rr[i]] + rk[i]] = make_int2(enode[ee[i]], __float_as_int(invc[ee[i]]));
}

// ---- RNE f32 -> bf16 packing (static indexing only) ----
static __device__ __forceinline__ bf16x8 rne8(float4 a, float4 b) {
    float f[8] = {a.x, a.y, a.z, a.w, b.x, b.y, b.z, b.w};
    union { unsigned short us[8]; bf16x8 v; } U;
    #pragma unroll
    for (int i = 0; i < 8; ++i) {
        unsigned u = __float_as_uint(f[i]);
        U.us[i] = (unsigned short)((u + 0x7fffu + ((u >> 16) & 1u)) >> 16);
    }
    return U.v;
}

static __device__ __forceinline__ bf16x8 rne8s(float4 a, float4 b, float s) {
    float f[8] = {a.x, a.y, a.z, a.w, b.x, b.y, b.z, b.w};
    union { unsigned short us[8]; bf16x8 v; } U;
    #pragma unroll
    for (int i = 0; i < 8; ++i) {
        unsigned u = __float_as_uint(f[i] * s);
        U.us[i] = (unsigned short)((u + 0x7fffu + ((u >> 16) & 1u)) >> 16);
    }
    return U.v;
}

// ---------------- W -> bf16 B-fragment precompute ----------------
// wf[(r*8 + j)*64 + lane], j = tt*2 + ks.
// Lane l (eh=l&15, kg=l>>4) holds W[r][16*tt + eh][32*ks + 8*kg + i], i=0..7.
__global__ void k_wfrag(const float* __restrict__ w, bf16x8* __restrict__ wf) {
    int r = blockIdx.x;
    int lane = threadIdx.x & 63;
    int eh = lane & 15, kg = lane >> 4;
    #pragma unroll
    for (int j = 0; j < 8; ++j) {
        int tt = j >> 1, ks = j & 1;
        const float4* p = reinterpret_cast<const float4*>(
            w + ((size_t)r << 12) + (size_t)(16 * tt + eh) * 64 + 32 * ks + 8 * kg);
        wf[(r * 8 + j) * 64 + lane] = rne8(p[0], p[1]);
    }
}

#define LOADB(rr) { \
    _Pragma("unroll") \
    for (int j_ = 0; j_ < 8; ++j_) B[j_] = wf[((rr) * 8 + j_) * 64 + lane]; }

// uniform bucket + real-end select chain (named scalars)
#define BUCKET(tslot, rr, rv) { \
    rr = 0; rv = re0; \
    if ((tslot) >= pf1) { rr = 1; rv = re1; } \
    if ((tslot) >= pf2) { rr = 2; rv = re2; } \
    if ((tslot) >= pf3) { rr = 3; rv = re3; } \
    if ((tslot) >= pf4) { rr = 4; rv = re4; } \
    if ((tslot) >= pf5) { rr = 5; rv = re5; } \
    if ((tslot) >= pf6) { rr = 6; rv = re6; } \
    if ((tslot) >= pf7) { rr = 7; rv = re7; } \
    if ((tslot) >= pf8) { rr = 8; rv = re8; } \
    if ((tslot) >= pf9) { rr = 9; rv = re9; } }

// ---------------- main compute ----------------
// Rating-sorted tiles (rating uniform per tile): 8 unmasked MFMAs per tile,
// B reloaded only at bucket boundaries (~1/wave). Batch-issue: 4 metas
// upfront, then 16 x-float4 gathers, then convert->MFMA->store per tile.
// Stable sort => ascending edge ids per bucket => each 256B embed row is
// fetched exactly once chip-wide. D (m89): row(edge)=4*kg+rg, col=16*tt+eh.
__global__ __launch_bounds__(256) void k_main(
    const float* __restrict__ embed, const bf16x8* __restrict__ wf,
    const int* __restrict__ poff, const int* __restrict__ rend,
    const int2* __restrict__ meta, float* __restrict__ out) {

    int lane = threadIdx.x & 63;
    int wv = threadIdx.x >> 6;
    int eh = lane & 15, kg = lane >> 4;

    int Tp = poff[NUM_RATINGS] >> 4;
    int t_base = (blockIdx.x * 4 + wv) * CH;
    if (t_base >= Tp) return;

    int pf1 = poff[1], pf2 = poff[2], pf3 = poff[3], pf4 = poff[4], pf5 = poff[5];
    int pf6 = poff[6], pf7 = poff[7], pf8 = poff[8], pf9 = poff[9];
    int re0 = rend[0], re1 = rend[1], re2 = rend[2], re3 = rend[3], re4 = rend[4];
    int re5 = rend[5], re6 = rend[6], re7 = rend[7], re8 = rend[8], re9 = rend[9];

    // 1) all CH meta loads upfront (independent)
    int R[CH]; int2 M[CH]; bool V[CH];
    #pragma unroll
    for (int it = 0; it < CH; ++it) {
        int t = t_base + it;
        int tslot = t << 4;
        int r_, rv_;
        BUCKET(tslot, r_, rv_);
        R[it] = r_;
        int slot = tslot + eh;
        bool valid = (t < Tp) && (slot < rv_);
        V[it] = valid;
        M[it] = meta[valid ? slot : 0];
    }

    // 2) all x gathers issued together (one dependent round trip total)
    float4 x0[CH], x1[CH], x2[CH], x3[CH];
    #pragma unroll
    for (int it = 0; it < CH; ++it) {
        int nd_ = V[it] ? M[it].x : 0;
        const float4* xp = reinterpret_cast<const float4*>(embed + ((size_t)nd_ << 6));
        x0[it] = xp[2 * kg];     x1[it] = xp[2 * kg + 1];
        x2[it] = xp[8 + 2 * kg]; x3[it] = xp[9 + 2 * kg];
    }

    bf16x8 B[8];
    int cur_r = R[0];
    LOADB(cur_r);

    // 3) per tile: convert (inv_c folded), 8 MFMAs, store
    #pragma unroll
    for (int it = 0; it < CH; ++it) {
        if (R[it] != cur_r) { cur_r = R[it]; LOADB(cur_r); }

        float s_ = V[it] ? __int_as_float(M[it].y) : 0.f;
        bf16x8 a0 = rne8s(x0[it], x1[it], s_);
        bf16x8 a1 = rne8s(x2[it], x3[it], s_);

        f32x4 acc[4];
        #pragma unroll
        for (int tt = 0; tt < 4; ++tt) acc[tt] = (f32x4){0.f, 0.f, 0.f, 0.f};
        #pragma unroll
        for (int tt = 0; tt < 4; ++tt) {
            acc[tt] = __builtin_amdgcn_mfma_f32_16x16x32_bf16(a0, B[2 * tt],     acc[tt], 0, 0, 0);
            acc[tt] = __builtin_amdgcn_mfma_f32_16x16x32_bf16(a1, B[2 * tt + 1], acc[tt], 0, 0, 0);
        }

        int vnd = V[it] ? M[it].x : -1;
        int kg4 = kg << 2;
        #pragma unroll
        for (int rg = 0; rg < 4; ++rg) {
            int nd2 = __shfl(vnd, kg4 + rg, 64);
            if (nd2 >= 0) {
                float* po = out + ((size_t)nd2 << 6) + eh;
                __builtin_nontemporal_store(acc[0][rg], po);
                __builtin_nontemporal_store(acc[1][rg], po + 16);
                __builtin_nontemporal_store(acc[2][rg], po + 32);
                __builtin_nontemporal_store(acc[3][rg], po + 48);
            }
        }
    }
}

extern "C" void kernel_launch(void* const* d_in, const int* in_sizes, int n_in,
                              void* d_out, int out_size, void* d_ws, size_t ws_size,
                              hipStream_t stream) {
    const float* embed   = (const float*)d_in[0];
    const float* weights = (const float*)d_in[1];
    const float* invc    = (const float*)d_in[2];
    const int*   enode   = (const int*)d_in[3];
    const int*   erating = (const int*)d_in[4];
    float* out = (float*)d_out;

    int E = in_sizes[3];

    char* ws = (char*)d_ws;
    int*    cnt    = (int*)ws;
    int*    poff   = cnt + 16;
    int*    cursor = cnt + 32;
    int*    rend   = cnt + 48;
    bf16x8* wf     = (bf16x8*)(ws + 256);            // 80 KiB
    int2*   meta   = (int2*)(ws + 256 + 81920);

    hipLaunchKernelGGL(k_zero, dim3(1), dim3(64), 0, stream, cnt);

    int hb = (E + 1023) / 1024;
    hipLaunchKernelGGL(k_hist, dim3(hb), dim3(256), 0, stream, erating, E, cnt);
    hipLaunchKernelGGL(k_prefix, dim3(1), dim3(64), 0, stream, cnt, poff, cursor, rend);
    hipLaunchKernelGGL(k_scatter, dim3(hb), dim3(256), 0, stream,
                       erating, enode, invc, E, cursor, meta);
    hipLaunchKernelGGL(k_wfrag, dim3(NUM_RATINGS), dim3(64), 0, stream, weights, wf);

    int Tp_up = (E + 15 * NUM_RATINGS + 15) / 16;
    int waves = (Tp_up + CH - 1) / CH;
    int blocks = (waves + 3) / 4;
    hipLaunchKernelGGL(k_main, dim3(blocks), dim3(256), 0, stream,
                       embed, wf, poff, rend, meta, out);
}

// Round 9
// 116.195 us; speedup vs baseline: 1.2927x; 1.2927x over previous
//
#include <hip/hip_runtime.h>
#include <hip/hip_bf16.h>

#define NUM_RATINGS 10
#define GW 2048   // persistent waves = 512 blocks x 4

typedef short bf16x8 __attribute__((ext_vector_type(8)));
typedef float f32x4 __attribute__((ext_vector_type(4)));

// ---- RNE f32 -> bf16 packing (static indexing only) ----
static __device__ __forceinline__ bf16x8 rne8(float4 a, float4 b) {
    float f[8] = {a.x, a.y, a.z, a.w, b.x, b.y, b.z, b.w};
    union { unsigned short us[8]; bf16x8 v; } U;
    #pragma unroll
    for (int i = 0; i < 8; ++i) {
        unsigned u = __float_as_uint(f[i]);
        U.us[i] = (unsigned short)((u + 0x7fffu + ((u >> 16) & 1u)) >> 16);
    }
    return U.v;
}

static __device__ __forceinline__ bf16x8 rne8s(float4 a, float4 b, float s) {
    float f[8] = {a.x, a.y, a.z, a.w, b.x, b.y, b.z, b.w};
    union { unsigned short us[8]; bf16x8 v; } U;
    #pragma unroll
    for (int i = 0; i < 8; ++i) {
        unsigned u = __float_as_uint(f[i] * s);
        U.us[i] = (unsigned short)((u + 0x7fffu + ((u >> 16) & 1u)) >> 16);
    }
    return U.v;
}

// ---------------- W -> bf16 B-fragment precompute (verified round 6) -------
// wf[(r*8 + j)*64 + lane], j = tt*2 + ks.
// Lane l (eh=l&15, kg=l>>4) holds W[r][16*tt + eh][32*ks + 8*kg + i], i=0..7.
__global__ void k_wfrag(const float* __restrict__ w, bf16x8* __restrict__ wf) {
    int r = blockIdx.x;
    int lane = threadIdx.x & 63;
    int eh = lane & 15, kg = lane >> 4;
    #pragma unroll
    for (int j = 0; j < 8; ++j) {
        int tt = j >> 1, ks = j & 1;
        const float4* p = reinterpret_cast<const float4*>(
            w + ((size_t)r << 12) + (size_t)(16 * tt + eh) * 64 + 32 * ks + 8 * kg);
        wf[(r * 8 + j) * 64 + lane] = rne8(p[0], p[1]);
    }
}

// meta generation S for chunk CC: per-lane edges (eh, eh+16) of the chunk
#define MLOAD(S, CC) { \
    int cc_ = (CC); if (cc_ > NCm1) cc_ = NCm1; \
    int b_ = cc_ * 32 + eh; \
    int ea_ = b_ > Em1 ? Em1 : b_; \
    int eb_ = (b_ + 16) > Em1 ? Em1 : (b_ + 16); \
    nd##S##0 = enode[ea_]; rt##S##0 = erating[ea_]; sc##S##0 = invc[ea_]; \
    nd##S##1 = enode[eb_]; rt##S##1 = erating[eb_]; sc##S##1 = invc[eb_]; }

// x set XS for the chunk whose meta is in MS
#define XLOADM(XS, MS) { \
    const float4* pa_ = reinterpret_cast<const float4*>(embed + ((size_t)nd##MS##0 << 6)); \
    const float4* pb_ = reinterpret_cast<const float4*>(embed + ((size_t)nd##MS##1 << 6)); \
    x##XS##00 = pa_[2 * kg]; x##XS##01 = pa_[2 * kg + 1]; \
    x##XS##02 = pa_[8 + 2 * kg]; x##XS##03 = pa_[9 + 2 * kg]; \
    x##XS##10 = pb_[2 * kg]; x##XS##11 = pb_[2 * kg + 1]; \
    x##XS##12 = pb_[8 + 2 * kg]; x##XS##13 = pb_[9 + 2 * kg]; }

// process chunk c (meta MP, x XC); prefetch x(c+GW) from MQ and meta(c+2GW) into MP
#define ITER(MP, MQ, XC, XN) { \
    XLOADM(XN, MQ) \
    int snd0 = nd##MP##0, snd1 = nd##MP##1; \
    int srt0 = rt##MP##0, srt1 = rt##MP##1; \
    float ssc0 = sc##MP##0, ssc1 = sc##MP##1; \
    bf16x8 a00 = rne8s(x##XC##00, x##XC##01, ssc0); \
    bf16x8 a01 = rne8s(x##XC##02, x##XC##03, ssc0); \
    bf16x8 a10 = rne8s(x##XC##10, x##XC##11, ssc1); \
    bf16x8 a11 = rne8s(x##XC##12, x##XC##13, ssc1); \
    MLOAD(MP, c + 2 * GW) \
    unsigned pres0 = 0, pres1 = 0; \
    _Pragma("unroll") \
    for (int rq = 0; rq < NUM_RATINGS; ++rq) { \
        if (__any(srt0 == rq)) pres0 |= 1u << rq; \
        if (__any(srt1 == rq)) pres1 |= 1u << rq; \
    } \
    f32x4 ac0[4], ac1[4]; \
    _Pragma("unroll") \
    for (int t_ = 0; t_ < 4; ++t_) { \
        ac0[t_] = (f32x4){0.f, 0.f, 0.f, 0.f}; \
        ac1[t_] = (f32x4){0.f, 0.f, 0.f, 0.f}; \
    } \
    _Pragma("unroll 1") \
    for (int r_ = 0; r_ < NUM_RATINGS; ++r_) { \
        if (!(((pres0 | pres1) >> r_) & 1u)) continue; \
        bf16x8 Bv[8]; \
        _Pragma("unroll") \
        for (int j_ = 0; j_ < 8; ++j_) Bv[j_] = swf[(r_ * 8 + j_) * 64 + lane]; \
        bf16x8 z_ = (bf16x8)(short)0; \
        if ((pres0 >> r_) & 1u) { \
            bf16x8 m0_ = (srt0 == r_) ? a00 : z_; \
            bf16x8 m1_ = (srt0 == r_) ? a01 : z_; \
            _Pragma("unroll") \
            for (int t_ = 0; t_ < 4; ++t_) { \
                ac0[t_] = __builtin_amdgcn_mfma_f32_16x16x32_bf16(m0_, Bv[2 * t_],     ac0[t_], 0, 0, 0); \
                ac0[t_] = __builtin_amdgcn_mfma_f32_16x16x32_bf16(m1_, Bv[2 * t_ + 1], ac0[t_], 0, 0, 0); \
            } \
        } \
        if ((pres1 >> r_) & 1u) { \
            bf16x8 m0_ = (srt1 == r_) ? a10 : z_; \
            bf16x8 m1_ = (srt1 == r_) ? a11 : z_; \
            _Pragma("unroll") \
            for (int t_ = 0; t_ < 4; ++t_) { \
                ac1[t_] = __builtin_amdgcn_mfma_f32_16x16x32_bf16(m0_, Bv[2 * t_],     ac1[t_], 0, 0, 0); \
                ac1[t_] = __builtin_amdgcn_mfma_f32_16x16x32_bf16(m1_, Bv[2 * t_ + 1], ac1[t_], 0, 0, 0); \
            } \
        } \
    } \
    int kg4 = kg << 2; \
    _Pragma("unroll") \
    for (int rg = 0; rg < 4; ++rg) { \
        int er0 = c * 32 + kg4 + rg; \
        int nda = __shfl(snd0, kg4 + rg, 64); \
        if (er0 < E) { \
            float* po = out + ((size_t)nda << 6) + eh; \
            __builtin_nontemporal_store(ac0[0][rg], po); \
            __builtin_nontemporal_store(ac0[1][rg], po + 16); \
            __builtin_nontemporal_store(ac0[2][rg], po + 32); \
            __builtin_nontemporal_store(ac0[3][rg], po + 48); \
        } \
        int er1 = c * 32 + 16 + kg4 + rg; \
        int ndb = __shfl(snd1, kg4 + rg, 64); \
        if (er1 < E) { \
            float* po = out + ((size_t)ndb << 6) + eh; \
            __builtin_nontemporal_store(ac1[0][rg], po); \
            __builtin_nontemporal_store(ac1[1][rg], po + 16); \
            __builtin_nontemporal_store(ac1[2][rg], po + 32); \
            __builtin_nontemporal_store(ac1[3][rg], po + 48); \
        } \
    } \
}

// ---------------- persistent main ----------------
// Natural edge order (coalesced IO), masked MFMA over present ratings,
// all-ratings B cached in LDS per block, 2-deep cross-chunk pipeline.
// D layout (m89, verified r4-r8): row(edge) = 4*kg + rg, col(out) = 16*tt + eh.
__global__ __launch_bounds__(256, 2) void k_main(
    const float* __restrict__ embed, const bf16x8* __restrict__ wf,
    const float* __restrict__ invc, const int* __restrict__ enode,
    const int* __restrict__ erating, float* __restrict__ out, int E) {

    __shared__ bf16x8 swf[NUM_RATINGS * 8 * 64];   // 80 KiB
    for (int i = threadIdx.x; i < NUM_RATINGS * 8 * 64; i += 256)
        swf[i] = wf[i];
    __syncthreads();

    int lane = threadIdx.x & 63;
    int wv = threadIdx.x >> 6;
    int eh = lane & 15, kg = lane >> 4;

    int NC = (E + 31) >> 5;
    int NCm1 = NC - 1, Em1 = E - 1;
    int c = blockIdx.x * 4 + wv;
    if (c >= NC) return;

    int ndP0, ndP1, rtP0, rtP1; float scP0, scP1;
    int ndQ0, ndQ1, rtQ0, rtQ1; float scQ0, scQ1;
    float4 xX00, xX01, xX02, xX03, xX10, xX11, xX12, xX13;
    float4 xY00, xY01, xY02, xY03, xY10, xY11, xY12, xY13;

    MLOAD(P, c)
    MLOAD(Q, c + GW)
    XLOADM(X, P)

    while (1) {
        ITER(P, Q, X, Y)
        c += GW; if (c >= NC) break;
        ITER(Q, P, Y, X)
        c += GW; if (c >= NC) break;
    }
}

extern "C" void kernel_launch(void* const* d_in, const int* in_sizes, int n_in,
                              void* d_out, int out_size, void* d_ws, size_t ws_size,
                              hipStream_t stream) {
    const float* embed   = (const float*)d_in[0];
    const float* weights = (const float*)d_in[1];
    const float* invc    = (const float*)d_in[2];
    const int*   enode   = (const int*)d_in[3];
    const int*   erating = (const int*)d_in[4];
    float* out = (float*)d_out;

    int E = in_sizes[3];

    bf16x8* wf = (bf16x8*)d_ws;   // 80 KiB W fragments

    hipLaunchKernelGGL(k_wfrag, dim3(NUM_RATINGS), dim3(64), 0, stream, weights, wf);
    hipLaunchKernelGGL(k_main, dim3(GW / 4), dim3(256), 0, stream,
                       embed, wf, invc, enode, erating, out, E);
}